// Round 4
// baseline (336.060 us; speedup 1.0000x reference)
//
#include <hip/hip_runtime.h>
#include <hip/hip_bf16.h>
#include <stdint.h>
#include <math.h>

#define DEVI __device__ __forceinline__

typedef __attribute__((ext_vector_type(8))) __bf16    bf16x8;
typedef __attribute__((ext_vector_type(8))) _Float16  f16x8;
typedef __attribute__((ext_vector_type(4))) float     f32x4;

constexpr int BM = 128, BN = 128, BK = 64;
// Packed-triangular S: tile (qt,kt), kt<=qt, at index qt*(qt+1)/2 + kt.
// Each tile 128x128 fp16 = 16384 elems. 136 tiles/batch.
constexpr int STILE  = 16384;
constexpr int SBATCH = 136 * STILE;   // 2,228,224 elems = 4,456,448 B

DEVI unsigned int pack2(float a, float b) {
  unsigned short ha = __builtin_bit_cast(unsigned short, __float2bfloat16(a));
  unsigned short hb = __builtin_bit_cast(unsigned short, __float2bfloat16(b));
  return (unsigned int)ha | ((unsigned int)hb << 16);
}

// ---------------------------------------------------------------------------
// Merged fp32 -> bf16 conversion for x, Wq, Wk, Wv in ONE launch.
// ---------------------------------------------------------------------------
__global__ __launch_bounds__(256) void k_cvt_all(const float* __restrict__ x,
                                                 const float* __restrict__ Wq,
                                                 const float* __restrict__ Wk,
                                                 const float* __restrict__ Wv,
                                                 __hip_bfloat16* __restrict__ xb,
                                                 __hip_bfloat16* __restrict__ Wqb,
                                                 __hip_bfloat16* __restrict__ Wkb,
                                                 __hip_bfloat16* __restrict__ Wvb) {
  int i = blockIdx.x * 256 + threadIdx.x;
  const float* src;
  __hip_bfloat16* dst;
  int k;
  if (i < 4194304) {
    src = x; dst = xb; k = i;
  } else {
    int j = i - 4194304;
    int w = j >> 18;
    k = j & 262143;
    src = (w == 0) ? Wq : (w == 1) ? Wk : Wv;
    dst = (w == 0) ? Wqb : (w == 1) ? Wkb : Wvb;
  }
  float4 f = ((const float4*)src)[k];
  uint2 u;
  u.x = pack2(f.x, f.y);
  u.y = pack2(f.z, f.w);
  ((uint2*)dst)[k] = u;
}

// ---------------------------------------------------------------------------
// Staging: global -> LDS via global_load_lds (16B/lane), wave-uniform LDS
// base. XOR swizzle on the GLOBAL column so ds_read_b128 fragment reads
// spread across banks. LDS (row,k) at row*64 + ((k/8)^(row&7))*8 + k%8.
// NR = number of 64-col rows staged (multiple of 32 with 256 threads).
// ---------------------------------------------------------------------------
template<int NR>
DEVI void stage_rows(const __hip_bfloat16* gbase, int ld, unsigned short* lds, int tid) {
#pragma unroll
  for (int j = 0; j < NR / 32; ++j) {
    int g   = j * 256 + tid;
    int row = g >> 3;
    int cp  = g & 7;
    int c   = cp ^ (row & 7);
    const __hip_bfloat16* src = gbase + (size_t)row * ld + c * 8;
    unsigned short* dst = lds + (size_t)(j * 256 + (tid & ~63)) * 8;  // wave-uniform
    __builtin_amdgcn_global_load_lds((__attribute__((address_space(1))) void*)(src),
                                     (__attribute__((address_space(3))) void*)(dst),
                                     16, 0, 0);
  }
}

DEVI void stage_tile(const __hip_bfloat16* gbase, int ld, unsigned short* lds, int tid) {
  stage_rows<128>(gbase, ld, lds, tid);
}

DEVI bf16x8 read_frag(const unsigned short* lds, int row, int kcol) {
  int c  = kcol >> 3;
  int cp = c ^ (row & 7);
  return *(const bf16x8*)(lds + row * 64 + cp * 8);
}

// ---------------------------------------------------------------------------
// 128x128x(64*ktiles) bf16 MFMA core, gemm_bt (proven; used by proj/scores).
// ---------------------------------------------------------------------------
DEVI void gemm_core(unsigned short* sA, unsigned short* sB,
                    const __hip_bfloat16* A0, int lda,
                    const __hip_bfloat16* B0, int ldb,
                    int ktiles, f32x4 (&acc)[4][4]) {
  const int tid  = threadIdx.x;
  const int lane = tid & 63;
  const int wid  = tid >> 6;
  const int quad = lane >> 4;
  const int lr   = lane & 15;
  const int wm   = (wid >> 1) * 64;
  const int wn   = (wid & 1) * 64;
  const f32x4 Z = {0.f, 0.f, 0.f, 0.f};
#pragma unroll
  for (int i = 0; i < 4; ++i)
#pragma unroll
    for (int j = 0; j < 4; ++j) acc[i][j] = Z;

  for (int kt = 0; kt < ktiles; ++kt) {
    stage_tile(A0 + kt * BK, lda, sA, tid);
    stage_tile(B0 + kt * BK, ldb, sB, tid);
    __syncthreads();
#pragma unroll
    for (int ks = 0; ks < BK; ks += 32) {
      bf16x8 af[4], bfr[4];
#pragma unroll
      for (int t = 0; t < 4; ++t) af[t]  = read_frag(sA, wm + t * 16 + lr, ks + quad * 8);
#pragma unroll
      for (int t = 0; t < 4; ++t) bfr[t] = read_frag(sB, wn + t * 16 + lr, ks + quad * 8);
#pragma unroll
      for (int i = 0; i < 4; ++i)
#pragma unroll
        for (int j = 0; j < 4; ++j)
          acc[i][j] = __builtin_amdgcn_mfma_f32_16x16x32_bf16(af[i], bfr[j], acc[i][j], 0, 0, 0);
    }
    __syncthreads();
  }
}

// ---------------------------------------------------------------------------
// Merged QKV projection (one launch, grid 3072). Inner XCD swizzle keeps a
// 4MB per-XCD X working set. V stored per-batch transposed Vt[b][e][s].
// (Proven: ~105 us, MfmaUtil ~44%.)
// ---------------------------------------------------------------------------
__global__ __launch_bounds__(256, 4) void k_proj_qkv(const __hip_bfloat16* __restrict__ X,
                                                     const __hip_bfloat16* __restrict__ Wq,
                                                     const __hip_bfloat16* __restrict__ Wk,
                                                     const __hip_bfloat16* __restrict__ Wv,
                                                     const float* __restrict__ bq,
                                                     const float* __restrict__ bk,
                                                     const float* __restrict__ bv,
                                                     __hip_bfloat16* __restrict__ Q,
                                                     __hip_bfloat16* __restrict__ Kp,
                                                     __hip_bfloat16* __restrict__ Vt) {
  __shared__ unsigned short sA[BM * BK];
  __shared__ unsigned short sB[BN * BK];
  const int id = blockIdx.x;
  const int w  = id >> 10;                    // 0=Q 1=K 2=V
  const int i2 = id & 1023;
  const int mt = ((i2 & 7) << 4) | ((i2 >> 3) & 15);
  const int nt = i2 >> 7;
  const int m0 = mt * BM;
  const int n0 = nt * BN;

  const __hip_bfloat16* W = (w == 0) ? Wq : (w == 1) ? Wk : Wv;
  const float* bias       = (w == 0) ? bq : (w == 1) ? bk : bv;

  f32x4 acc[4][4];
  gemm_core(sA, sB, X + (size_t)m0 * 1024, 1024, W + (size_t)n0 * 1024, 1024, 16, acc);

  const int tid = threadIdx.x, lane = tid & 63, wid = tid >> 6;
  const int quad = lane >> 4, lr = lane & 15;
  const int wm = (wid >> 1) * 64, wn = (wid & 1) * 64;
  float bvv[4];
#pragma unroll
  for (int j = 0; j < 4; ++j) bvv[j] = bias[n0 + wn + j * 16 + lr];

  if (w != 2) {
    __hip_bfloat16* C = (w == 0) ? Q : Kp;
#pragma unroll
    for (int i = 0; i < 4; ++i)
#pragma unroll
      for (int j = 0; j < 4; ++j) {
        int n = n0 + wn + j * 16 + lr;
#pragma unroll
        for (int r = 0; r < 4; ++r) {
          int m = m0 + wm + i * 16 + quad * 4 + r;
          C[(size_t)m * 1024 + n] = __float2bfloat16(acc[i][j][r] + bvv[j]);
        }
      }
  } else {
    const int b = m0 >> 11;
    __hip_bfloat16* Cb = Vt + ((size_t)b << 21);
    const int sb = (m0 & 2047) + wm;
#pragma unroll
    for (int i = 0; i < 4; ++i)
#pragma unroll
      for (int j = 0; j < 4; ++j) {
        int n  = n0 + wn + j * 16 + lr;
        int s0 = sb + i * 16 + quad * 4;
        uint2 u;
        u.x = pack2(acc[i][j][0] + bvv[j], acc[i][j][1] + bvv[j]);
        u.y = pack2(acc[i][j][2] + bvv[j], acc[i][j][3] + bvv[j]);
        *(uint2*)(Cb + (size_t)n * 2048 + s0) = u;
      }
  }
}

// ---------------------------------------------------------------------------
// Scores: packed-triangular S[z], tile (qt,kt) fp16 = (Q.K)/32.
// Grid 8*136; z = id & 7 (batch <-> XCD), triangular tile decode.
// ---------------------------------------------------------------------------
__global__ __launch_bounds__(256, 4) void k_scores(const __hip_bfloat16* __restrict__ Q,
                                                   const __hip_bfloat16* __restrict__ Kmat,
                                                   _Float16* __restrict__ S) {
  __shared__ unsigned short sA[BM * BK];
  __shared__ unsigned short sB[BN * BK];
  const int id = blockIdx.x;
  const int z = id & 7;
  const int i = id >> 3;
  int qt = (int)((sqrtf(8.f * (float)i + 1.f) - 1.f) * 0.5f);
  while ((qt + 1) * (qt + 2) / 2 <= i) ++qt;
  while (qt * (qt + 1) / 2 > i) --qt;
  const int kt = i - qt * (qt + 1) / 2;

  const int m0 = qt * BM, n0 = kt * BN;
  f32x4 acc[4][4];
  const __hip_bfloat16* A0 = Q    + ((size_t)z << 21) + (size_t)m0 * 1024;
  const __hip_bfloat16* B0 = Kmat + ((size_t)z << 21) + (size_t)n0 * 1024;
  gemm_core(sA, sB, A0, 1024, B0, 1024, 16, acc);

  _Float16* St = S + (size_t)z * SBATCH + (size_t)i * STILE;  // i == tri(qt)+kt
  const int tid = threadIdx.x, lane = tid & 63, wid = tid >> 6;
  const int quad = lane >> 4, lr = lane & 15;
  const int wm = (wid >> 1) * 64, wn = (wid & 1) * 64;
#pragma unroll
  for (int i2 = 0; i2 < 4; ++i2)
#pragma unroll
    for (int j = 0; j < 4; ++j) {
      int n = wn + j * 16 + lr;                       // col within tile
#pragma unroll
      for (int r = 0; r < 4; ++r) {
        int m = wm + i2 * 16 + quad * 4 + r;          // row within tile
        St[(size_t)m * 128 + n] = (_Float16)(acc[i2][j][r] * 0.03125f);
      }
    }
}

// ---------------------------------------------------------------------------
// Row softmax over the packed-triangular S, in-place fp16 -> bf16.
// ONE WAVE PER ROW (4 rows/block, no LDS). Row q touches tiles
// tri(qt)..tri(qt)+qt (qt = q>>7), i.e. cols [0, (qt+1)*128) only —
// no zero-fill writes beyond the diagonal tile. Grid 8*512; z = id & 7.
// ---------------------------------------------------------------------------
__global__ __launch_bounds__(256) void k_softmax(_Float16* __restrict__ S) {
  const int id   = blockIdx.x;
  const int z    = id & 7;
  const int r    = id >> 3;            // 0..511
  const int wid  = threadIdx.x >> 6;
  const int lane = threadIdx.x & 63;
  const int q    = r * 4 + wid;
  const int qt   = q >> 7;
  const int mr   = q & 127;
  const int len  = (qt + 1) << 7;      // valid cols
  const int tri  = (qt * (qt + 1)) >> 1;
  _Float16* Sz = S + (size_t)z * SBATCH;

  float v[4][8];
  float mx = -1e30f;
#pragma unroll
  for (int it = 0; it < 4; ++it) {
    int c = it * 512 + lane * 8;       // global col of first elem
    if (c < len && c <= q) {
      int kt  = c >> 7;
      int off = c & 127;
      f16x8 h = *(const f16x8*)(Sz + (size_t)(tri + kt) * STILE + (size_t)mr * 128 + off);
#pragma unroll
      for (int i = 0; i < 8; ++i) {
        float f = (float)h[i];
        v[it][i] = (c + i <= q) ? f : -1e30f;
        mx = fmaxf(mx, v[it][i]);
      }
    } else {
#pragma unroll
      for (int i = 0; i < 8; ++i) v[it][i] = -1e30f;
    }
  }
#pragma unroll
  for (int off = 32; off > 0; off >>= 1) mx = fmaxf(mx, __shfl_xor(mx, off));

  float e[4][8], s = 0.f;
#pragma unroll
  for (int it = 0; it < 4; ++it)
#pragma unroll
    for (int i = 0; i < 8; ++i) { e[it][i] = __expf(v[it][i] - mx); s += e[it][i]; }
#pragma unroll
  for (int off = 32; off > 0; off >>= 1) s += __shfl_xor(s, off);
  const float inv = 1.0f / s;

#pragma unroll
  for (int it = 0; it < 4; ++it) {
    int c = it * 512 + lane * 8;
    if (c < len) {
      bf16x8 o;
#pragma unroll
      for (int i = 0; i < 8; ++i) o[i] = (__bf16)(e[it][i] * inv);
      int kt  = c >> 7;
      int off = c & 127;
      *(bf16x8*)(Sz + (size_t)(tri + kt) * STILE + (size_t)mr * 128 + off) = o;
    }
  }
}

// ---------------------------------------------------------------------------
// PV: out[b,q,e] = sum_s P[q,s]*Vt[e,s], fp32 out. BM=128, BN=64; P staged
// from packed-triangular tiles (ld=128). Grid 8*128 (pairs p x 16 n-tiles)
// = 4 blocks/CU. Load-balanced pairing: (qt=15-p, nt) then (qt=p, nt).
// ---------------------------------------------------------------------------
DEVI void pv_core(unsigned short* sA, unsigned short* sB,
                  const __hip_bfloat16* Pz, int qt,
                  const __hip_bfloat16* B0,
                  f32x4 (&acc)[4][2]) {
  const int tid  = threadIdx.x;
  const int lane = tid & 63;
  const int wid  = tid >> 6;
  const int quad = lane >> 4;
  const int lr   = lane & 15;
  const int wm   = (wid >> 1) * 64;
  const int wn   = (wid & 1) * 32;
  const int tri  = (qt * (qt + 1)) >> 1;
  const int ktiles = 2 * qt + 2;       // covers s in [0, (qt+1)*128)
  const f32x4 Z = {0.f, 0.f, 0.f, 0.f};
#pragma unroll
  for (int i = 0; i < 4; ++i)
#pragma unroll
    for (int j = 0; j < 2; ++j) acc[i][j] = Z;

  for (int kt = 0; kt < ktiles; ++kt) {
    const __hip_bfloat16* At = Pz + (size_t)(tri + (kt >> 1)) * STILE + (kt & 1) * 64;
    stage_rows<128>(At, 128, sA, tid);
    stage_rows<64> (B0 + kt * BK, 2048, sB, tid);
    __syncthreads();
#pragma unroll
    for (int ks = 0; ks < BK; ks += 32) {
      bf16x8 af[4], bfr[2];
#pragma unroll
      for (int t = 0; t < 4; ++t) af[t]  = read_frag(sA, wm + t * 16 + lr, ks + quad * 8);
#pragma unroll
      for (int t = 0; t < 2; ++t) bfr[t] = read_frag(sB, wn + t * 16 + lr, ks + quad * 8);
#pragma unroll
      for (int i = 0; i < 4; ++i)
#pragma unroll
        for (int j = 0; j < 2; ++j)
          acc[i][j] = __builtin_amdgcn_mfma_f32_16x16x32_bf16(af[i], bfr[j], acc[i][j], 0, 0, 0);
    }
    __syncthreads();
  }
}

DEVI void pv_one(unsigned short* sA, unsigned short* sB,
                 const __hip_bfloat16* Pz, const __hip_bfloat16* VtB,
                 float* Cb, int qt, int nt) {
  const int m0 = qt * BM, n0 = nt * 64;
  f32x4 acc[4][2];
  pv_core(sA, sB, Pz, qt, VtB + (size_t)n0 * 2048, acc);

  const int tid = threadIdx.x, lane = tid & 63, wid = tid >> 6;
  const int quad = lane >> 4, lr = lane & 15;
  const int wm = (wid >> 1) * 64, wn = (wid & 1) * 32;
#pragma unroll
  for (int i = 0; i < 4; ++i)
#pragma unroll
    for (int j = 0; j < 2; ++j) {
      int n = n0 + wn + j * 16 + lr;
#pragma unroll
      for (int r = 0; r < 4; ++r) {
        int m = m0 + wm + i * 16 + quad * 4 + r;
        Cb[(size_t)m * 1024 + n] = acc[i][j][r];
      }
    }
}

__global__ __launch_bounds__(256, 4) void k_pv(const _Float16* __restrict__ Sbase,
                                               const __hip_bfloat16* __restrict__ Vt,
                                               float* __restrict__ out) {
  __shared__ unsigned short sA[BM * BK];
  __shared__ unsigned short sB[64 * BK];
  const int id = blockIdx.x;
  const int z = id & 7;
  const int r2 = id >> 3;          // 0..127
  const int nt = r2 & 15;
  const int p  = (r2 >> 4) & 7;
  const __hip_bfloat16* Pz  = (const __hip_bfloat16*)(Sbase + (size_t)z * SBATCH);
  const __hip_bfloat16* VtB = Vt + ((size_t)z << 21);
  float* Cb = out + ((size_t)z << 21);
  pv_one(sA, sB, Pz, VtB, Cb, 15 - p, nt);   // long tile first
  pv_one(sA, sB, Pz, VtB, Cb, p, nt);        // short tile second
}

extern "C" void kernel_launch(void* const* d_in, const int* in_sizes, int n_in,
                              void* d_out, int out_size, void* d_ws, size_t ws_size,
                              hipStream_t stream) {
  const float* x  = (const float*)d_in[0];
  const float* Wq = (const float*)d_in[1];
  const float* bq = (const float*)d_in[2];
  const float* Wk = (const float*)d_in[3];
  const float* bk = (const float*)d_in[4];
  const float* Wv = (const float*)d_in[5];
  const float* bv = (const float*)d_in[6];
  float* out = (float*)d_out;

  char* ws = (char*)d_ws;
  const size_t MB32 = (size_t)33554432;

  // Layout (140.5 MiB, same as proven small layout):
  //   [xb 32MB][Wqb 2MB][Wkb 2MB][Wvb 2MB][Q 32MB][Kp 32MB][Vt 32MB]
  // Packed-triangular S (35.65MB, all 8 batches) overlays xb+Wqb+Wkb,
  // which are dead once k_proj_qkv completes.
  _Float16*       S   = (_Float16*)(ws);
  __hip_bfloat16* xb  = (__hip_bfloat16*)(ws);
  __hip_bfloat16* Wqb = (__hip_bfloat16*)(ws + MB32);
  __hip_bfloat16* Wkb = (__hip_bfloat16*)(ws + MB32 + 2097152);
  __hip_bfloat16* Wvb = (__hip_bfloat16*)(ws + MB32 + 4194304);
  __hip_bfloat16* Q   = (__hip_bfloat16*)(ws + MB32 + 6291456);
  __hip_bfloat16* Kp  = (__hip_bfloat16*)(ws + 2 * MB32 + 6291456);
  __hip_bfloat16* Vt  = (__hip_bfloat16*)(ws + 3 * MB32 + 6291456);

  dim3 blk(256);
  k_cvt_all<<<dim3(19456), blk, 0, stream>>>(x, Wq, Wk, Wv, xb, Wqb, Wkb, Wvb);
  k_proj_qkv<<<dim3(3072), blk, 0, stream>>>(xb, Wqb, Wkb, Wvb, bq, bk, bv, Q, Kp, Vt);
  k_scores <<<dim3(8 * 136), blk, 0, stream>>>(Q, Kp, S);
  k_softmax<<<dim3(8 * 512), blk, 0, stream>>>(S);
  k_pv     <<<dim3(8 * 128), blk, 0, stream>>>(S, Vt, out);
}